// Round 7
// baseline (923.599 us; speedup 1.0000x reference)
//
#include <hip/hip_runtime.h>

// MoE fused kernel, MI355X gfx950 — Round 10: ZERO in-loop barriers.
// Shapes: B=65536, D=512, C=101, E=8, H=256.
// out[b,c] = sum_{e,h} g[b,e]*relu(x@W1+b1)[b,e,h]*W2[e,h,c] + sum_e g[b,e]*b2[e,c]
// g = softmax(x@Wg+bg), gate logits folded into layer1 GEMM as cols 2048..2055.
//
// R9 post-mortem: row-split cut LDS but doubled W1-L2 and 4x'd W2-L2 (B-reuse
// lost) -> 455us. REVERTED. Consolidated model now fits R7/R8/R9: per-CU
// MFMA 81us + LDS ~100-127us + L2 78us ~= serial sum = 257us measured. The
// pipes don't overlap because 8 in-loop barriers phase-lock all waves (LDS
// phase together, MFMA phase together...). R7's 2-blocks/CU didn't help for
// the same reason. R10 removes ALL in-loop barriers: hA wave-private again ->
// layer2 K-split -> acc2[4][7]=112 persistent regs. R5 spilled this at cap
// 170; at launch_bounds(512,2) cap=256, tally ~217 fits. Layer2 reads only
// own 4KB h' (LDS 1.8->0.13MB/block), b-frags 1 wave each (L2 unchanged).
// Waves drift -> MFMA/LDS/L2 overlap statistically. End: 4-phase cross-wave
// reduction through xA-reuse (50KB), 9 barriers total post-loop.
// Spill tripwire: WRITE_SIZE >100MB => acc2 spilled => revert to ct-owned.
//
// MFMA layouts (m89/m120-verified):
//   A: A[m][k], m=lane&15, k=(lane>>4)*8+j (j=0..7)
//   B: B[k][n], n=lane&15, k=(lane>>4)*8+j
//   C/D: col=lane&15, row=(lane>>4)*4+reg

typedef __attribute__((ext_vector_type(8))) short short8x;
typedef __attribute__((ext_vector_type(4))) float float4x;

#define C_DIM 101

__device__ __forceinline__ unsigned short f2bf(float f) {
  unsigned int u = __builtin_bit_cast(unsigned int, f);
  u += 0x7fffu + ((u >> 16) & 1u);     // round-to-nearest-even
  return (unsigned short)(u >> 16);
}

// ---- merged weight conversion (one launch)
// W1 (+Wg) -> bf16 B-frags: frag = ntile*16+kf ; elem = frag*512 + lane*8 + j
// W2       -> bf16 B-frags: frag = ntile*64+kf ; ntile 0..7, kf 0..63 (K=2048)
__global__ void conv_weights(const float* __restrict__ W1, const float* __restrict__ Wg,
                             const float* __restrict__ W2,
                             unsigned short* __restrict__ W1bf,
                             unsigned short* __restrict__ W2bf) {
  if (blockIdx.x < 516) {
    int s = blockIdx.x * blockDim.x + threadIdx.x;   // slot = frag*64 + lane
    int l = s & 63;
    int frag = s >> 6;
    int kf = frag & 15;
    int ntile = frag >> 4;
    int n = (ntile << 4) | (l & 15);
    int k = (kf << 5) | ((l >> 4) << 3);
    short8x v;
#pragma unroll
    for (int j = 0; j < 8; ++j) {
      int kk = k + j;
      float f;
      if (n < 2048)      f = W1[((size_t)(n >> 8) * 512 + kk) * 256 + (n & 255)];
      else if (n < 2056) f = Wg[(size_t)kk * 8 + (n - 2048)];
      else               f = 0.f;
      v[j] = (short)f2bf(f);
    }
    *(short8x*)(W1bf + (size_t)s * 8) = v;
  } else {
    int s = (blockIdx.x - 516) * blockDim.x + threadIdx.x;
    int l = s & 63;
    int frag = s >> 6;
    int kf = frag & 63;
    int ntile = frag >> 6;
    int c = (ntile << 4) | (l & 15);
    int k = (kf << 5) | ((l >> 4) << 3);
    short8x v;
#pragma unroll
    for (int j = 0; j < 8; ++j) {
      int kk = k + j;                       // e = kk>>8, h = kk&255
      float f = (c < C_DIM) ? W2[((size_t)(kk >> 8) * 256 + (kk & 255)) * C_DIM + c] : 0.f;
      v[j] = (short)f2bf(f);
    }
    *(short8x*)(W2bf + (size_t)s * 8) = v;
  }
}

// ---- fused main kernel: 64 rows/block, 512 threads (8 waves), 1 block/CU
__global__ __launch_bounds__(512, 2) void moe_main(
    const float* __restrict__ x, const float* __restrict__ b1,
    const float* __restrict__ b2, const float* __restrict__ bg,
    const unsigned short* __restrict__ W1bf, const unsigned short* __restrict__ W2bf,
    float* __restrict__ out) {
  __shared__ unsigned short xA[64 * 512];   // 64 KB: x A-frags [mt*16+kf][lane*8+j]
  __shared__ unsigned short hA[8 * 4 * 512];// 16 KB: 8 waves x wave-private 4 h' frags
  __shared__ float gt[8 * 64];              //  2 KB: gates^T [e][row]
  float* graw = (float*)hA;                 // raw gate logits [64][8]; pre-loop only
  float* red  = (float*)xA;                 // end reduction: 7ct x 7src x 64l x 16B = 50KB

  const int tid = threadIdx.x;
  const int w = tid >> 6;     // wave 0..7
  const int l = tid & 63;     // lane
  const int quad = l >> 4;
  const int p = l & 15;
  const int r0 = blockIdx.x * 64;
  unsigned short* hAw = hA + w * 4 * 512;   // wave-private: 4 frags (4 KB)

  // ---- stage x -> bf16 A-frag LDS (coalesced float4 x2 reads, b128 LDS writes)
#pragma unroll
  for (int it = 0; it < 8; ++it) {
    int g = tid + it * 512;            // m = g>>6 (0..63), k0 = (g&63)*8
    int m = g >> 6;
    int k0 = (g & 63) << 3;
    const float* src = x + (size_t)(r0 + m) * 512 + k0;
    float4 f0 = *(const float4*)src;
    float4 f1 = *(const float4*)(src + 4);
    short8x v;
    v[0] = (short)f2bf(f0.x); v[1] = (short)f2bf(f0.y);
    v[2] = (short)f2bf(f0.z); v[3] = (short)f2bf(f0.w);
    v[4] = (short)f2bf(f1.x); v[5] = (short)f2bf(f1.y);
    v[6] = (short)f2bf(f1.z); v[7] = (short)f2bf(f1.w);
    int mt = m >> 4;
    int kfrag = k0 >> 5;
    int lane = (((k0 >> 3) & 3) << 4) | (m & 15);
    *(short8x*)&xA[(size_t)(((mt << 4) | kfrag) * 64 + lane) * 8] = v;
  }
  __syncthreads();

  // ---- gate logits: waves 0..3 each do one 16-row tile x 16 gate cols (ntile 128)
  if (w < 4) {
    float4x acc = {0.f, 0.f, 0.f, 0.f};
#pragma unroll 2
    for (int kf = 0; kf < 16; ++kf) {
      short8x a = *(const short8x*)&xA[(size_t)((w * 16 + kf) * 64 + l) * 8];
      short8x b = *(const short8x*)(W1bf + ((size_t)(128 * 16 + kf) * 512 + l * 8));
      acc = __builtin_amdgcn_mfma_f32_16x16x32_bf16(a, b, acc, 0, 0, 0);
    }
    if (p < 8) {
      float bgv = bg[p];
#pragma unroll
      for (int r = 0; r < 4; ++r)
        graw[(w * 16 + quad * 4 + r) * 8 + p] = acc[r] + bgv;
    }
  }
  __syncthreads();
  // softmax over E=8 per row, fp32; write transposed gt[e][row]
  if (tid < 64) {
    float v[8], mx = -1e30f;
#pragma unroll
    for (int e = 0; e < 8; ++e) { v[e] = graw[tid * 8 + e]; mx = fmaxf(mx, v[e]); }
    float s = 0.f;
#pragma unroll
    for (int e = 0; e < 8; ++e) { v[e] = expf(v[e] - mx); s += v[e]; }
    float inv = 1.f / s;
#pragma unroll
    for (int e = 0; e < 8; ++e) gt[e * 64 + tid] = v[e] * inv;
  }
  __syncthreads();   // graw (hA alias) reads done before first hAw write
  // ======== NO MORE BARRIERS UNTIL AFTER THE EXPERT LOOP ========

  float4x zero = {0.f, 0.f, 0.f, 0.f};
  float4x acc2[4][7];                    // [mt][ct] K-sliced partial; 112 VGPRs
#pragma unroll
  for (int mt = 0; mt < 4; ++mt)
#pragma unroll
    for (int ct = 0; ct < 7; ++ct) acc2[mt][ct] = zero;

  for (int e = 0; e < 8; ++e) {
    // layer1: wave w covers h-cols [e*256 + w*32, +32), all 64 rows
    float4x acc1[4][2];                  // [mt][nc]
#pragma unroll
    for (int mt = 0; mt < 4; ++mt) { acc1[mt][0] = zero; acc1[mt][1] = zero; }

    const unsigned short* __restrict__ bp =
        W1bf + ((size_t)(e * 16 + w * 2) * 16) * 512 + (size_t)l * 8;
    // nc stride = 16 frags * 512 = 8192 shorts; kf stride = 512 shorts
    short8x bA0 = *(const short8x*)(bp);
    short8x bA1 = *(const short8x*)(bp + 8192);
    short8x bB0, bB1;
#pragma unroll
    for (int kf = 0; kf < 16; kf += 2) {
      bB0 = *(const short8x*)(bp + (kf + 1) * 512);
      bB1 = *(const short8x*)(bp + 8192 + (kf + 1) * 512);
#pragma unroll
      for (int mt = 0; mt < 4; ++mt) {
        short8x a = *(const short8x*)&xA[(size_t)((mt * 16 + kf) * 64 + l) * 8];
        acc1[mt][0] = __builtin_amdgcn_mfma_f32_16x16x32_bf16(a, bA0, acc1[mt][0], 0, 0, 0);
        acc1[mt][1] = __builtin_amdgcn_mfma_f32_16x16x32_bf16(a, bA1, acc1[mt][1], 0, 0, 0);
      }
      if (kf + 2 < 16) {
        bA0 = *(const short8x*)(bp + (kf + 2) * 512);
        bA1 = *(const short8x*)(bp + 8192 + (kf + 2) * 512);
      }
#pragma unroll
      for (int mt = 0; mt < 4; ++mt) {
        short8x a = *(const short8x*)&xA[(size_t)((mt * 16 + kf + 1) * 64 + l) * 8];
        acc1[mt][0] = __builtin_amdgcn_mfma_f32_16x16x32_bf16(a, bB0, acc1[mt][0], 0, 0, 0);
        acc1[mt][1] = __builtin_amdgcn_mfma_f32_16x16x32_bf16(a, bB1, acc1[mt][1], 0, 0, 0);
      }
    }

    // epilogue: +b1, relu, *gate(e), bf16 -> WAVE-PRIVATE hAw (C->A transpose)
    // wave's 32 h-cols = its K-slice (kf2 = e*8 + w); frag index = mt
    float4x gv0 = *(const float4x*)&gt[e * 64 + 0  + quad * 4];
    float4x gv1 = *(const float4x*)&gt[e * 64 + 16 + quad * 4];
    float4x gv2 = *(const float4x*)&gt[e * 64 + 32 + quad * 4];
    float4x gv3 = *(const float4x*)&gt[e * 64 + 48 + quad * 4];
#pragma unroll
    for (int nc = 0; nc < 2; ++nc) {
      int cw = w * 32 + nc * 16 + p;     // h-col within expert tile (0..255)
      float b1v = b1[e * 256 + cw];
      int jj = p & 7;
      int ldbase = ((nc * 2 + (p >> 3)) << 4);   // (koff>>3)*16, koff = nc*16+p
#pragma unroll
      for (int mt = 0; mt < 4; ++mt) {
        float4x gv = (mt == 0) ? gv0 : (mt == 1) ? gv1 : (mt == 2) ? gv2 : gv3;
#pragma unroll
        for (int r = 0; r < 4; ++r) {
          float hv = fmaxf(acc1[mt][nc][r] + b1v, 0.f) * gv[r];
          hAw[(size_t)mt * 512 + (ldbase + quad * 4 + r) * 8 + jj] = f2bf(hv);
        }
      }
    }

    // layer2 partial: own K-slice (32 h-cols, 1 K-frag) x 7 ct, all 4 mt.
    // a-frags read once (own 4KB), reused across 7 ct; each b read by 1 wave.
    short8x am0 = *(const short8x*)&hAw[(size_t)0 * 512 + l * 8];
    short8x am1 = *(const short8x*)&hAw[(size_t)1 * 512 + l * 8];
    short8x am2 = *(const short8x*)&hAw[(size_t)2 * 512 + l * 8];
    short8x am3 = *(const short8x*)&hAw[(size_t)3 * 512 + l * 8];
    const unsigned short* __restrict__ bp2 =
        W2bf + ((size_t)(e * 8 + w)) * 512 + (size_t)l * 8;
#pragma unroll
    for (int ct = 0; ct < 7; ++ct) {
      short8x b = *(const short8x*)(bp2 + (size_t)ct * 64 * 512);
      acc2[0][ct] = __builtin_amdgcn_mfma_f32_16x16x32_bf16(am0, b, acc2[0][ct], 0, 0, 0);
      acc2[1][ct] = __builtin_amdgcn_mfma_f32_16x16x32_bf16(am1, b, acc2[1][ct], 0, 0, 0);
      acc2[2][ct] = __builtin_amdgcn_mfma_f32_16x16x32_bf16(am2, b, acc2[2][ct], 0, 0, 0);
      acc2[3][ct] = __builtin_amdgcn_mfma_f32_16x16x32_bf16(am3, b, acc2[3][ct], 0, 0, 0);
    }
  }

  // ---- end: cross-wave reduction of K-sliced acc2 (red reuses xA), +bias, store
  // wave w owns ct=w (w<7); contributors to ct: the 7 waves != ct, slot s bijective
  __syncthreads();                       // all waves done with xA reads
#pragma unroll
  for (int mt = 0; mt < 4; ++mt) {
#pragma unroll
    for (int ct = 0; ct < 7; ++ct) {
      if (ct != w) {
        int s = w - (w > ct ? 1 : 0);    // 0..6
        *(float4x*)&red[((ct * 7 + s) * 64 + l) * 4] = acc2[mt][ct];
      }
    }
    __syncthreads();
    if (w < 7) {
      float4x sum = acc2[mt][w];
#pragma unroll
      for (int s = 0; s < 7; ++s)
        sum += *(const float4x*)&red[((w * 7 + s) * 64 + l) * 4];
      int c = w * 16 + p;
      if (c < C_DIM) {
#pragma unroll
        for (int r = 0; r < 4; ++r) {
          int row = mt * 16 + quad * 4 + r;
          float bias = 0.f;
#pragma unroll
          for (int e = 0; e < 8; ++e) bias += gt[e * 64 + row] * b2[e * C_DIM + c];
          out[(size_t)(r0 + row) * C_DIM + c] = sum[r] + bias;
        }
      }
    }
    __syncthreads();                     // reads done before next mt overwrites red
  }
}

extern "C" void kernel_launch(void* const* d_in, const int* in_sizes, int n_in,
                              void* d_out, int out_size, void* d_ws, size_t ws_size,
                              hipStream_t stream) {
  const float* x  = (const float*)d_in[0];
  const float* W1 = (const float*)d_in[1];
  const float* b1 = (const float*)d_in[2];
  const float* W2 = (const float*)d_in[3];
  const float* b2 = (const float*)d_in[4];
  const float* Wg = (const float*)d_in[5];
  const float* bg = (const float*)d_in[6];
  float* out = (float*)d_out;

  unsigned short* W1bf = (unsigned short*)d_ws;
  unsigned short* W2bf = (unsigned short*)((char*)d_ws + (size_t)129 * 16 * 512 * 2);

  conv_weights<<<644, 256, 0, stream>>>(W1, Wg, W2, W1bf, W2bf);  // 516 + 128 blocks
  moe_main<<<1024, 512, 0, stream>>>(x, b1, b2, bg, W1bf, W2bf, out);
}

// Round 8
// 377.348 us; speedup vs baseline: 2.4476x; 2.4476x over previous
//
#include <hip/hip_runtime.h>

// MoE fused kernel, MI355X gfx950 — Round 11: R8 + full 1-step operand pipeline.
// Shapes: B=65536, D=512, C=101, E=8, H=256.
// out[b,c] = sum_{e,h} g[b,e]*relu(x@W1+b1)[b,e,h]*W2[e,h,c] + sum_e g[b,e]*b2[e,c]
// g = softmax(x@Wg+bg), gate logits folded into layer1 GEMM as cols 2048..2055.
//
// R10 post-mortem: K-sliced acc2[4][7] spilled AGAIN (870MB writes, VGPR
// pinned 128) — third kill (R3/R5/R10); ct-owned layer2 is now an absolute
// rule. Model refit (R7-R10): layer1 kf-step per CU = LDS 385cy + MFMA 310cy
// + L2 286cy SERIAL (~980; MfmaUtil 28% ≈ 310/980 matches). Serialization
// cause is NOT barriers (none in kf loop) but the ds_read->MFMA dependency:
// a-frags read immediately before use; 2 waves/SIMD stall at the same point.
// R11 = R8 exactly (ct-owned acc2[4], 8 in-loop barriers, Mtile=64, 130KB
// LDS, 1 blk/CU) + ONE-STEP SOFTWARE PIPELINE on all operand reads: layer1
// prefetches a[4]+b[2] one kf ahead (R8 only did b); layer2 prefetches
// a[4]+b[1] one step ahead. Every MFMA consumes regs loaded a full step
// earlier -> ds_read/global_load overlap MFMA; ideal step max(385,310) vs
// 980 serial. Regs: acc1 32 + acc2 16 + a-dbuf 32 + b-dbuf 16 + temps ~160
// < 256 cap. Tripwire: WRITE_SIZE >100MB = spill = back off.
// Null branch: dur~250 & MfmaUtil~28 & VGPR up => compiler already pipelined,
// LDS-throughput-bound => R12 = 32x32x16 MFMA (halves operand B/FLOP).
//
// MFMA layouts (m89/m120-verified):
//   A: A[m][k], m=lane&15, k=(lane>>4)*8+j (j=0..7)
//   B: B[k][n], n=lane&15, k=(lane>>4)*8+j
//   C/D: col=lane&15, row=(lane>>4)*4+reg

typedef __attribute__((ext_vector_type(8))) short short8x;
typedef __attribute__((ext_vector_type(4))) float float4x;

#define C_DIM 101

__device__ __forceinline__ unsigned short f2bf(float f) {
  unsigned int u = __builtin_bit_cast(unsigned int, f);
  u += 0x7fffu + ((u >> 16) & 1u);     // round-to-nearest-even
  return (unsigned short)(u >> 16);
}

// ---- merged weight conversion (one launch)
// W1 (+Wg) -> bf16 B-frags: frag = ntile*16+kf ; elem = frag*512 + lane*8 + j
// W2       -> bf16 B-frags: frag = ntile*64+kf ; ntile 0..7, kf 0..63 (K=2048)
__global__ void conv_weights(const float* __restrict__ W1, const float* __restrict__ Wg,
                             const float* __restrict__ W2,
                             unsigned short* __restrict__ W1bf,
                             unsigned short* __restrict__ W2bf) {
  if (blockIdx.x < 516) {
    int s = blockIdx.x * blockDim.x + threadIdx.x;   // slot = frag*64 + lane
    int l = s & 63;
    int frag = s >> 6;
    int kf = frag & 15;
    int ntile = frag >> 4;
    int n = (ntile << 4) | (l & 15);
    int k = (kf << 5) | ((l >> 4) << 3);
    short8x v;
#pragma unroll
    for (int j = 0; j < 8; ++j) {
      int kk = k + j;
      float f;
      if (n < 2048)      f = W1[((size_t)(n >> 8) * 512 + kk) * 256 + (n & 255)];
      else if (n < 2056) f = Wg[(size_t)kk * 8 + (n - 2048)];
      else               f = 0.f;
      v[j] = (short)f2bf(f);
    }
    *(short8x*)(W1bf + (size_t)s * 8) = v;
  } else {
    int s = (blockIdx.x - 516) * blockDim.x + threadIdx.x;
    int l = s & 63;
    int frag = s >> 6;
    int kf = frag & 63;
    int ntile = frag >> 6;
    int c = (ntile << 4) | (l & 15);
    int k = (kf << 5) | ((l >> 4) << 3);
    short8x v;
#pragma unroll
    for (int j = 0; j < 8; ++j) {
      int kk = k + j;                       // e = kk>>8, h = kk&255
      float f = (c < C_DIM) ? W2[((size_t)(kk >> 8) * 256 + (kk & 255)) * C_DIM + c] : 0.f;
      v[j] = (short)f2bf(f);
    }
    *(short8x*)(W2bf + (size_t)s * 8) = v;
  }
}

// ---- fused main kernel: 64 rows/block, 512 threads (8 waves), 1 block/CU
__global__ __launch_bounds__(512, 2) void moe_main(
    const float* __restrict__ x, const float* __restrict__ b1,
    const float* __restrict__ b2, const float* __restrict__ bg,
    const unsigned short* __restrict__ W1bf, const unsigned short* __restrict__ W2bf,
    float* __restrict__ out) {
  __shared__ unsigned short xA[64 * 512];   // 64 KB: x A-frags [mt*16+kf][lane*8+j]
  __shared__ unsigned short hA[64 * 512];   // 64 KB: 2 experts x 32 h' A-frags
  __shared__ float gt[8 * 64];              //  2 KB: gates^T [e][row]
  float* graw = (float*)hA;                 // raw gate logits [64][8]; pre-loop only

  const int tid = threadIdx.x;
  const int w = tid >> 6;     // wave 0..7
  const int l = tid & 63;     // lane
  const int quad = l >> 4;
  const int p = l & 15;
  const int r0 = blockIdx.x * 64;

  // ---- stage x -> bf16 A-frag LDS (coalesced float4 x2 reads, b128 LDS writes)
#pragma unroll
  for (int it = 0; it < 8; ++it) {
    int g = tid + it * 512;            // m = g>>6 (0..63), k0 = (g&63)*8
    int m = g >> 6;
    int k0 = (g & 63) << 3;
    const float* src = x + (size_t)(r0 + m) * 512 + k0;
    float4 f0 = *(const float4*)src;
    float4 f1 = *(const float4*)(src + 4);
    short8x v;
    v[0] = (short)f2bf(f0.x); v[1] = (short)f2bf(f0.y);
    v[2] = (short)f2bf(f0.z); v[3] = (short)f2bf(f0.w);
    v[4] = (short)f2bf(f1.x); v[5] = (short)f2bf(f1.y);
    v[6] = (short)f2bf(f1.z); v[7] = (short)f2bf(f1.w);
    int mt = m >> 4;
    int kfrag = k0 >> 5;
    int lane = (((k0 >> 3) & 3) << 4) | (m & 15);
    *(short8x*)&xA[(size_t)(((mt << 4) | kfrag) * 64 + lane) * 8] = v;
  }
  __syncthreads();

  // ---- gate logits: waves 0..3 each do one 16-row tile x 16 gate cols (ntile 128)
  if (w < 4) {
    float4x acc = {0.f, 0.f, 0.f, 0.f};
#pragma unroll 2
    for (int kf = 0; kf < 16; ++kf) {
      short8x a = *(const short8x*)&xA[(size_t)((w * 16 + kf) * 64 + l) * 8];
      short8x b = *(const short8x*)(W1bf + ((size_t)(128 * 16 + kf) * 512 + l * 8));
      acc = __builtin_amdgcn_mfma_f32_16x16x32_bf16(a, b, acc, 0, 0, 0);
    }
    if (p < 8) {
      float bgv = bg[p];
#pragma unroll
      for (int r = 0; r < 4; ++r)
        graw[(w * 16 + quad * 4 + r) * 8 + p] = acc[r] + bgv;
    }
  }
  __syncthreads();
  // softmax over E=8 per row, fp32; write transposed gt[e][row]
  if (tid < 64) {
    float v[8], mx = -1e30f;
#pragma unroll
    for (int e = 0; e < 8; ++e) { v[e] = graw[tid * 8 + e]; mx = fmaxf(mx, v[e]); }
    float s = 0.f;
#pragma unroll
    for (int e = 0; e < 8; ++e) { v[e] = expf(v[e] - mx); s += v[e]; }
    float inv = 1.f / s;
#pragma unroll
    for (int e = 0; e < 8; ++e) gt[e * 64 + tid] = v[e] * inv;
  }
  __syncthreads();   // graw (hA alias) reads done before first hA write

  // ---- main loop: 4 iterations, 2 experts each. acc2 = ct-owned full-K sum.
  float4x zero = {0.f, 0.f, 0.f, 0.f};
  float4x acc2[4];                       // [mt]; wave w owns output col-tile ct=w (w<7)
  acc2[0] = zero; acc2[1] = zero; acc2[2] = zero; acc2[3] = zero;

  for (int it = 0; it < 4; ++it) {
#pragma unroll
    for (int eo = 0; eo < 2; ++eo) {
      const int e = it * 2 + eo;
      // layer1: wave w covers h-cols [e*256 + w*32, +32), all 64 rows.
      // ONE-STEP PIPELINE: a[4]+b[2] for kf+1 issued before MFMAs of kf.
      float4x acc1[4][2];                // [mt][nc]
#pragma unroll
      for (int mt = 0; mt < 4; ++mt) { acc1[mt][0] = zero; acc1[mt][1] = zero; }

      const unsigned short* __restrict__ bp =
          W1bf + ((size_t)(e * 16 + w * 2) * 16) * 512 + (size_t)l * 8;
      // nc stride = 16 frags * 512 = 8192 shorts; kf stride = 512 shorts
      short8x aC0 = *(const short8x*)&xA[(size_t)((0 * 16 + 0) * 64 + l) * 8];
      short8x aC1 = *(const short8x*)&xA[(size_t)((1 * 16 + 0) * 64 + l) * 8];
      short8x aC2 = *(const short8x*)&xA[(size_t)((2 * 16 + 0) * 64 + l) * 8];
      short8x aC3 = *(const short8x*)&xA[(size_t)((3 * 16 + 0) * 64 + l) * 8];
      short8x bC0 = *(const short8x*)(bp);
      short8x bC1 = *(const short8x*)(bp + 8192);
#pragma unroll
      for (int kf = 0; kf < 16; ++kf) {
        short8x aN0, aN1, aN2, aN3, bN0, bN1;
        if (kf < 15) {
          bN0 = *(const short8x*)(bp + (kf + 1) * 512);
          bN1 = *(const short8x*)(bp + 8192 + (kf + 1) * 512);
          aN0 = *(const short8x*)&xA[(size_t)((0 * 16 + kf + 1) * 64 + l) * 8];
          aN1 = *(const short8x*)&xA[(size_t)((1 * 16 + kf + 1) * 64 + l) * 8];
          aN2 = *(const short8x*)&xA[(size_t)((2 * 16 + kf + 1) * 64 + l) * 8];
          aN3 = *(const short8x*)&xA[(size_t)((3 * 16 + kf + 1) * 64 + l) * 8];
        }
        acc1[0][0] = __builtin_amdgcn_mfma_f32_16x16x32_bf16(aC0, bC0, acc1[0][0], 0, 0, 0);
        acc1[1][0] = __builtin_amdgcn_mfma_f32_16x16x32_bf16(aC1, bC0, acc1[1][0], 0, 0, 0);
        acc1[2][0] = __builtin_amdgcn_mfma_f32_16x16x32_bf16(aC2, bC0, acc1[2][0], 0, 0, 0);
        acc1[3][0] = __builtin_amdgcn_mfma_f32_16x16x32_bf16(aC3, bC0, acc1[3][0], 0, 0, 0);
        acc1[0][1] = __builtin_amdgcn_mfma_f32_16x16x32_bf16(aC0, bC1, acc1[0][1], 0, 0, 0);
        acc1[1][1] = __builtin_amdgcn_mfma_f32_16x16x32_bf16(aC1, bC1, acc1[1][1], 0, 0, 0);
        acc1[2][1] = __builtin_amdgcn_mfma_f32_16x16x32_bf16(aC2, bC1, acc1[2][1], 0, 0, 0);
        acc1[3][1] = __builtin_amdgcn_mfma_f32_16x16x32_bf16(aC3, bC1, acc1[3][1], 0, 0, 0);
        if (kf < 15) {
          aC0 = aN0; aC1 = aN1; aC2 = aN2; aC3 = aN3;
          bC0 = bN0; bC1 = bN1;
        }
      }

      if (eo == 0) __syncthreads();      // BAR1: prev iteration's layer2 hA reads done

      // epilogue: +b1, relu, *gate(e), bf16 -> hA[eo] (C->A transpose)
      // wave w's 32 cols form exactly K-frag kf2=w; frag = eo*32 + w*4 + mt
      float4x gv0 = *(const float4x*)&gt[e * 64 + 0  + quad * 4];
      float4x gv1 = *(const float4x*)&gt[e * 64 + 16 + quad * 4];
      float4x gv2 = *(const float4x*)&gt[e * 64 + 32 + quad * 4];
      float4x gv3 = *(const float4x*)&gt[e * 64 + 48 + quad * 4];
#pragma unroll
      for (int nc = 0; nc < 2; ++nc) {
        int cw = w * 32 + nc * 16 + p;   // col within expert tile (0..255)
        float b1v = b1[e * 256 + cw];
        int jj = p & 7;
        int ldbase = ((nc * 2 + (p >> 3)) << 4);   // (koff>>3)*16, koff = nc*16+p
#pragma unroll
        for (int mt = 0; mt < 4; ++mt) {
          float4x gv = (mt == 0) ? gv0 : (mt == 1) ? gv1 : (mt == 2) ? gv2 : gv3;
#pragma unroll
          for (int r = 0; r < 4; ++r) {
            float hv = fmaxf(acc1[mt][nc][r] + b1v, 0.f) * gv[r];
            hA[(size_t)((eo * 32 + w * 4 + mt) * 512) + (ldbase + quad * 4 + r) * 8 + jj] =
                f2bf(hv);
          }
        }
      }
    }
    __syncthreads();                     // BAR2: both experts' h' published

    // layer2: wave w (<7) accumulates ct=w over both experts' K=512.
    // ONE-STEP PIPELINE over 16 flat steps s = eo*8+kf2: a[4]+b[1] ahead.
    if (w < 7) {
      const unsigned short* __restrict__ bp2 =
          W2bf + ((size_t)(w * 64 + it * 16)) * 512 + (size_t)l * 8;
      // W2 frag offset from bp2 = s*512 ; hA a-frag index = s*4 + mt
      short8x b2C = *(const short8x*)(bp2);
      short8x a2C0 = *(const short8x*)&hA[(size_t)((0 * 4 + 0) * 64 + l) * 8];
      short8x a2C1 = *(const short8x*)&hA[(size_t)((0 * 4 + 1) * 64 + l) * 8];
      short8x a2C2 = *(const short8x*)&hA[(size_t)((0 * 4 + 2) * 64 + l) * 8];
      short8x a2C3 = *(const short8x*)&hA[(size_t)((0 * 4 + 3) * 64 + l) * 8];
#pragma unroll
      for (int s = 0; s < 16; ++s) {
        short8x b2N, a2N0, a2N1, a2N2, a2N3;
        if (s < 15) {
          b2N = *(const short8x*)(bp2 + (size_t)(s + 1) * 512);
          a2N0 = *(const short8x*)&hA[(size_t)(((s + 1) * 4 + 0) * 64 + l) * 8];
          a2N1 = *(const short8x*)&hA[(size_t)(((s + 1) * 4 + 1) * 64 + l) * 8];
          a2N2 = *(const short8x*)&hA[(size_t)(((s + 1) * 4 + 2) * 64 + l) * 8];
          a2N3 = *(const short8x*)&hA[(size_t)(((s + 1) * 4 + 3) * 64 + l) * 8];
        }
        acc2[0] = __builtin_amdgcn_mfma_f32_16x16x32_bf16(a2C0, b2C, acc2[0], 0, 0, 0);
        acc2[1] = __builtin_amdgcn_mfma_f32_16x16x32_bf16(a2C1, b2C, acc2[1], 0, 0, 0);
        acc2[2] = __builtin_amdgcn_mfma_f32_16x16x32_bf16(a2C2, b2C, acc2[2], 0, 0, 0);
        acc2[3] = __builtin_amdgcn_mfma_f32_16x16x32_bf16(a2C3, b2C, acc2[3], 0, 0, 0);
        if (s < 15) {
          a2C0 = a2N0; a2C1 = a2N1; a2C2 = a2N2; a2C3 = a2N3;
          b2C = b2N;
        }
      }
    }
  }

  // ---- epilogue: + gate-weighted b2, store. No cross-wave reduction.
  if (w < 7) {
    int c = w * 16 + p;
    if (c < C_DIM) {
#pragma unroll
      for (int mt = 0; mt < 4; ++mt) {
#pragma unroll
        for (int r = 0; r < 4; ++r) {
          int row = mt * 16 + quad * 4 + r;
          float bias = 0.f;
#pragma unroll
          for (int e = 0; e < 8; ++e) bias += gt[e * 64 + row] * b2[e * C_DIM + c];
          out[(size_t)(r0 + row) * C_DIM + c] = acc2[mt][r] + bias;
        }
      }
    }
  }
}

extern "C" void kernel_launch(void* const* d_in, const int* in_sizes, int n_in,
                              void* d_out, int out_size, void* d_ws, size_t ws_size,
                              hipStream_t stream) {
  const float* x  = (const float*)d_in[0];
  const float* W1 = (const float*)d_in[1];
  const float* b1 = (const float*)d_in[2];
  const float* W2 = (const float*)d_in[3];
  const float* b2 = (const float*)d_in[4];
  const float* Wg = (const float*)d_in[5];
  const float* bg = (const float*)d_in[6];
  float* out = (float*)d_out;

  unsigned short* W1bf = (unsigned short*)d_ws;
  unsigned short* W2bf = (unsigned short*)((char*)d_ws + (size_t)129 * 16 * 512 * 2);

  conv_weights<<<644, 256, 0, stream>>>(W1, Wg, W2, W1bf, W2bf);  // 516 + 128 blocks
  moe_main<<<1024, 512, 0, stream>>>(x, b1, b2, bg, W1bf, W2bf, out);
}